// Round 2
// baseline (1423.744 us; speedup 1.0000x reference)
//
#include <hip/hip_runtime.h>
#include <hip/hip_bf16.h>
#include <cstdint>
#include <cstddef>

// Problem constants (B=2, N=1024, C=512, H=8, hd=64, clusters=8)
#define NB   2
#define NN   1024
#define NC   512
#define NH   8
#define NHD  64
#define NK   8

typedef __attribute__((ext_vector_type(8))) short short8v;   // 8 bf16 (4 VGPRs)
typedef __attribute__((ext_vector_type(4))) short short4v;
typedef __attribute__((ext_vector_type(4))) float f32x4;

__device__ __forceinline__ short f2bf(float f) {
    union { float f; unsigned u; } v; v.f = f;
    unsigned r = v.u + 0x7FFFu + ((v.u >> 16) & 1u);   // RNE
    return (short)(r >> 16);
}
__device__ __forceinline__ float bf2f(short s) {
    union { unsigned u; float f; } v;
    v.u = ((unsigned)(unsigned short)s) << 16;
    return v.f;
}

// ---------------------------------------------------------------- cast f32->bf16 (+ zero rowsum)
__global__ __launch_bounds__(256) void cast_kernel(
    const float* __restrict__ x, const float* __restrict__ wq,
    const float* __restrict__ wk, const float* __restrict__ wv,
    const float* __restrict__ wp,
    short* __restrict__ xb, short* __restrict__ wqb, short* __restrict__ wkb,
    short* __restrict__ wvb, short* __restrict__ wpb,
    float* __restrict__ rowsum) {
    int i = blockIdx.x * 256 + threadIdx.x;
    if (i < NB * NN * NC) xb[i] = f2bf(x[i]);
    if (i < NC * NC) {
        wqb[i] = f2bf(wq[i]);
        wkb[i] = f2bf(wk[i]);
        wvb[i] = f2bf(wv[i]);
        wpb[i] = f2bf(wp[i]);
    }
    if (i < NB * NH * NN) rowsum[i] = 0.f;
}

// ---------------------------------------------------------------- QKV GEMM
// q/k: (2048,512) bf16.  v stored transposed per head: vT[b,h,d,i] bf16.
__global__ __launch_bounds__(256) void qkv_kernel(
    const short* __restrict__ xb, const short* __restrict__ wqb,
    const short* __restrict__ wkb, const short* __restrict__ wvb,
    short* __restrict__ qb, short* __restrict__ kb, short* __restrict__ vT) {
    __shared__ short As[64][40];
    __shared__ short Bs[64][40];
    const int tid = threadIdx.x;
    const int z = blockIdx.z;
    const short* Bsrc = (z == 0) ? wqb : ((z == 1) ? wkb : wvb);
    const int m0 = blockIdx.y * 64, n0 = blockIdx.x * 64;
    const int lane = tid & 63, wave = tid >> 6;
    const int wm = wave >> 1, wn = wave & 1, quad = lane >> 4, lr = lane & 15;
    const int row = tid >> 2, c0 = (tid & 3) * 8;
    f32x4 acc[2][2] = {};
    for (int kt = 0; kt < 512; kt += 32) {
        *(short8v*)&As[row][c0] = *(const short8v*)(xb + (m0 + row) * 512 + kt + c0);
        *(short8v*)&Bs[row][c0] = *(const short8v*)(Bsrc + (n0 + row) * 512 + kt + c0);
        __syncthreads();
        short8v a0 = *(short8v*)&As[wm * 32 + lr][quad * 8];
        short8v a1 = *(short8v*)&As[wm * 32 + 16 + lr][quad * 8];
        short8v b0 = *(short8v*)&Bs[wn * 32 + lr][quad * 8];
        short8v b1 = *(short8v*)&Bs[wn * 32 + 16 + lr][quad * 8];
        acc[0][0] = __builtin_amdgcn_mfma_f32_16x16x32_bf16(a0, b0, acc[0][0], 0, 0, 0);
        acc[0][1] = __builtin_amdgcn_mfma_f32_16x16x32_bf16(a0, b1, acc[0][1], 0, 0, 0);
        acc[1][0] = __builtin_amdgcn_mfma_f32_16x16x32_bf16(a1, b0, acc[1][0], 0, 0, 0);
        acc[1][1] = __builtin_amdgcn_mfma_f32_16x16x32_bf16(a1, b1, acc[1][1], 0, 0, 0);
        __syncthreads();
    }
    for (int sm = 0; sm < 2; sm++)
        for (int sn = 0; sn < 2; sn++)
            for (int r = 0; r < 4; r++) {
                int m = m0 + wm * 32 + sm * 16 + quad * 4 + r;
                int n = n0 + wn * 32 + sn * 16 + lr;
                short v = f2bf(acc[sm][sn][r]);
                if (z == 0) qb[m * 512 + n] = v;
                else if (z == 1) kb[m * 512 + n] = v;
                else {
                    int bb = m >> 10, i = m & 1023, h = n >> 6, d = n & 63;
                    vT[(size_t)(((bb * 8 + h) * 64 + d) << 10) + i] = v;
                }
            }
}

// ---------------------------------------------------------------- colsum of v per (b,h): colsum[bh*64+d] = sum_j vT[bh,d,j]
__global__ __launch_bounds__(256) void colsum_kernel(
    const short* __restrict__ vT, float* __restrict__ colsum) {
    __shared__ float cp[64][5];
    const int bh = blockIdx.x, t = threadIdx.x;
    const int d = t >> 2, seg = t & 3;
    const short* p = vT + (((size_t)(bh * 64 + d)) << 10) + seg * 256;
    float s = 0.f;
    for (int k = 0; k < 256; k += 8) {
        short8v v = *(const short8v*)(p + k);
        for (int j = 0; j < 8; j++) s += bf2f(v[j]);
    }
    cp[d][seg] = s;
    __syncthreads();
    if (t < 64) colsum[bh * 64 + t] = cp[t][0] + cp[t][1] + cp[t][2] + cp[t][3];
}

// ---------------------------------------------------------------- fused scores + mask + attn_map scatter + exp
// Computes s = scale*q k^T for a 64x64 tile, writes all 8 cluster slices of
// attn_map (nontemporal), writes e=exp(masked s) bf16, atomically adds row sums.
__global__ __launch_bounds__(256) void scores_attn_kernel(
    const short* __restrict__ qb, const short* __restrict__ kb,
    const int* __restrict__ idx, float* __restrict__ attn,
    short* __restrict__ eb, float* __restrict__ rowsum) {
    __shared__ short As[64][72];
    __shared__ short Bs[64][72];
    __shared__ float Ss[64][68];
    __shared__ int idxi[64], idxj[64];
    __shared__ float rowpart[64][5];
    const int tid = threadIdx.x;
    const int z = blockIdx.z;            // b*8 + h
    const int b = z >> 3, h = z & 7;
    const int i0 = blockIdx.y * 64, j0 = blockIdx.x * 64;
    const int lane = tid & 63, wave = tid >> 6;
    const int wm = wave >> 1, wn = wave & 1, quad = lane >> 4, lr = lane & 15;
    {
        int r0 = tid >> 3, cc = (tid & 7) * 8;
        *(short8v*)&As[r0][cc]      = *(const short8v*)(qb + (b * 1024 + i0 + r0) * 512 + h * 64 + cc);
        *(short8v*)&As[r0 + 32][cc] = *(const short8v*)(qb + (b * 1024 + i0 + r0 + 32) * 512 + h * 64 + cc);
        *(short8v*)&Bs[r0][cc]      = *(const short8v*)(kb + (b * 1024 + j0 + r0) * 512 + h * 64 + cc);
        *(short8v*)&Bs[r0 + 32][cc] = *(const short8v*)(kb + (b * 1024 + j0 + r0 + 32) * 512 + h * 64 + cc);
        if (tid < 64) idxi[tid] = idx[b * 1024 + i0 + tid];
        else if (tid < 128) idxj[tid - 64] = idx[b * 1024 + j0 + (tid - 64)];
    }
    __syncthreads();
    f32x4 acc[2][2] = {};
    for (int k0 = 0; k0 < 64; k0 += 32) {
        short8v a0 = *(short8v*)&As[wm * 32 + lr][k0 + quad * 8];
        short8v a1 = *(short8v*)&As[wm * 32 + 16 + lr][k0 + quad * 8];
        short8v b0 = *(short8v*)&Bs[wn * 32 + lr][k0 + quad * 8];
        short8v b1 = *(short8v*)&Bs[wn * 32 + 16 + lr][k0 + quad * 8];
        acc[0][0] = __builtin_amdgcn_mfma_f32_16x16x32_bf16(a0, b0, acc[0][0], 0, 0, 0);
        acc[0][1] = __builtin_amdgcn_mfma_f32_16x16x32_bf16(a0, b1, acc[0][1], 0, 0, 0);
        acc[1][0] = __builtin_amdgcn_mfma_f32_16x16x32_bf16(a1, b0, acc[1][0], 0, 0, 0);
        acc[1][1] = __builtin_amdgcn_mfma_f32_16x16x32_bf16(a1, b1, acc[1][1], 0, 0, 0);
    }
    // s tile -> LDS (scaled)
    for (int sm = 0; sm < 2; sm++)
        for (int sn = 0; sn < 2; sn++)
            for (int r = 0; r < 4; r++)
                Ss[wm * 32 + sm * 16 + quad * 4 + r][wn * 32 + sn * 16 + lr] = acc[sm][sn][r] * 0.125f;
    __syncthreads();
    // epilogue: thread t -> row iL = t>>2, 16 cols starting at (t&3)*16
    const int iL = tid >> 2, jb = (tid & 3) * 16;
    const int ci = idxi[iL];
    const size_t abase = (((size_t)(b * 64 + h)) << 20) + (((size_t)(i0 + iL)) << 10) + j0 + jb;
    float rsum = 0.f;
    short8v e8[2];
    const f32x4 zero4 = {0.f, 0.f, 0.f, 0.f};
    for (int chunk = 0; chunk < 4; chunk++) {
        const int jc = jb + chunk * 4;
        f32x4 s4 = *(f32x4*)&Ss[iL][jc];
        f32x4 m4;
        for (int kk = 0; kk < 4; kk++) {
            const bool in = (idxj[jc + kk] == ci);
            const float sv = s4[kk];
            m4[kk] = in ? sv : 0.f;
            const float ev = (in && sv != 0.f) ? __expf(sv) : 0.f;
            rsum += ev;
            e8[chunk >> 1][(chunk & 1) * 4 + kk] = f2bf(ev);
        }
        float* base = attn + abase + chunk * 4;
        for (int c = 0; c < 8; c++) {
            f32x4 w = (c == ci) ? m4 : zero4;
            __builtin_nontemporal_store(w, (f32x4*)(base + ((size_t)c << 23)));
        }
    }
    short* erow = eb + ((((size_t)z << 10) + i0 + iL) << 10) + j0 + jb;
    *(short8v*)erow = e8[0];
    *(short8v*)(erow + 8) = e8[1];
    rowpart[iL][tid & 3] = rsum;
    __syncthreads();
    if (tid < 64) {
        float v = rowpart[tid][0] + rowpart[tid][1] + rowpart[tid][2] + rowpart[tid][3];
        atomicAdd(&rowsum[(z << 10) + i0 + tid], v);
    }
}

// ---------------------------------------------------------------- PV GEMM: oh = inv * (e @ v + epsN*colsum)
__global__ __launch_bounds__(256) void pv_kernel(
    const short* __restrict__ eb, const short* __restrict__ vT,
    const float* __restrict__ rowsum, const float* __restrict__ colsum,
    short* __restrict__ oh) {
    __shared__ short As[64][40];
    __shared__ short Bs[64][40];
    __shared__ float invL[64], csL[64];
    const int tid = threadIdx.x;
    const int z = blockIdx.z;            // b*8+h
    const int b = z >> 3, h = z & 7;
    const int i0 = blockIdx.y * 64;
    const int lane = tid & 63, wave = tid >> 6;
    const int wm = wave >> 1, wn = wave & 1, quad = lane >> 4, lr = lane & 15;
    const int row = tid >> 2, c0 = (tid & 3) * 8;
    if (tid < 64) invL[tid] = 1.f / (rowsum[(z << 10) + i0 + tid] + 1e-6f);
    else if (tid < 128) csL[tid - 64] = colsum[z * 64 + (tid - 64)];
    const short* Abase = eb + ((size_t)(z * 1024 + i0) << 10);
    const short* Bbase = vT + ((size_t)z << 16);
    f32x4 acc[2][2] = {};
    for (int kt = 0; kt < 1024; kt += 32) {
        *(short8v*)&As[row][c0] = *(const short8v*)(Abase + ((size_t)row << 10) + kt + c0);
        *(short8v*)&Bs[row][c0] = *(const short8v*)(Bbase + ((size_t)row << 10) + kt + c0);
        __syncthreads();
        short8v a0 = *(short8v*)&As[wm * 32 + lr][quad * 8];
        short8v a1 = *(short8v*)&As[wm * 32 + 16 + lr][quad * 8];
        short8v b0 = *(short8v*)&Bs[wn * 32 + lr][quad * 8];
        short8v b1 = *(short8v*)&Bs[wn * 32 + 16 + lr][quad * 8];
        acc[0][0] = __builtin_amdgcn_mfma_f32_16x16x32_bf16(a0, b0, acc[0][0], 0, 0, 0);
        acc[0][1] = __builtin_amdgcn_mfma_f32_16x16x32_bf16(a0, b1, acc[0][1], 0, 0, 0);
        acc[1][0] = __builtin_amdgcn_mfma_f32_16x16x32_bf16(a1, b0, acc[1][0], 0, 0, 0);
        acc[1][1] = __builtin_amdgcn_mfma_f32_16x16x32_bf16(a1, b1, acc[1][1], 0, 0, 0);
        __syncthreads();
    }
    const float epsN = 1e-6f / 1024.f;
    for (int sm = 0; sm < 2; sm++)
        for (int sn = 0; sn < 2; sn++)
            for (int r = 0; r < 4; r++) {
                int iLoc = wm * 32 + sm * 16 + quad * 4 + r;
                int d = wn * 32 + sn * 16 + lr;
                float val = (acc[sm][sn][r] + epsN * csL[d]) * invL[iLoc];
                oh[((size_t)(b * 1024 + i0 + iLoc)) * 512 + h * 64 + d] = f2bf(val);
            }
}

// ---------------------------------------------------------------- proj GEMM + bias
__global__ __launch_bounds__(256) void proj_kernel(
    const short* __restrict__ oh, const short* __restrict__ wpb,
    const float* __restrict__ bias, float* __restrict__ out) {
    __shared__ short As[64][40];
    __shared__ short Bs[64][40];
    const int tid = threadIdx.x;
    const int m0 = blockIdx.y * 64, n0 = blockIdx.x * 64;
    const int lane = tid & 63, wave = tid >> 6;
    const int wm = wave >> 1, wn = wave & 1, quad = lane >> 4, lr = lane & 15;
    const int row = tid >> 2, c0 = (tid & 3) * 8;
    f32x4 acc[2][2] = {};
    for (int kt = 0; kt < 512; kt += 32) {
        *(short8v*)&As[row][c0] = *(const short8v*)(oh + (m0 + row) * 512 + kt + c0);
        *(short8v*)&Bs[row][c0] = *(const short8v*)(wpb + (n0 + row) * 512 + kt + c0);
        __syncthreads();
        short8v a0 = *(short8v*)&As[wm * 32 + lr][quad * 8];
        short8v a1 = *(short8v*)&As[wm * 32 + 16 + lr][quad * 8];
        short8v b0 = *(short8v*)&Bs[wn * 32 + lr][quad * 8];
        short8v b1 = *(short8v*)&Bs[wn * 32 + 16 + lr][quad * 8];
        acc[0][0] = __builtin_amdgcn_mfma_f32_16x16x32_bf16(a0, b0, acc[0][0], 0, 0, 0);
        acc[0][1] = __builtin_amdgcn_mfma_f32_16x16x32_bf16(a0, b1, acc[0][1], 0, 0, 0);
        acc[1][0] = __builtin_amdgcn_mfma_f32_16x16x32_bf16(a1, b0, acc[1][0], 0, 0, 0);
        acc[1][1] = __builtin_amdgcn_mfma_f32_16x16x32_bf16(a1, b1, acc[1][1], 0, 0, 0);
        __syncthreads();
    }
    for (int sm = 0; sm < 2; sm++)
        for (int sn = 0; sn < 2; sn++)
            for (int r = 0; r < 4; r++) {
                int m = m0 + wm * 32 + sm * 16 + quad * 4 + r;
                int n = n0 + wn * 32 + sn * 16 + lr;
                out[(size_t)m * 512 + n] = acc[sm][sn][r] + bias[n];
            }
}

// ---------------------------------------------------------------- launch
extern "C" void kernel_launch(void* const* d_in, const int* in_sizes, int n_in,
                              void* d_out, int out_size, void* d_ws, size_t ws_size,
                              hipStream_t stream) {
    const float* x     = (const float*)d_in[0];
    const int*   idx   = (const int*)d_in[2];
    const float* Wq    = (const float*)d_in[4];
    const float* Wk    = (const float*)d_in[5];
    const float* Wv    = (const float*)d_in[6];
    const float* Wp    = (const float*)d_in[7];
    const float* bproj = (const float*)d_in[8];

    float* out  = (float*)d_out;
    float* attn = out + (size_t)NB * NN * NC;   // attn_map region (B,K,H,N,N)

    char* ws = (char*)d_ws;
    short* xb  = (short*)(ws + 0);           // 2 MB
    short* wqb = (short*)(ws + 2097152);     // 512 KB
    short* wkb = (short*)(ws + 2621440);
    short* wvb = (short*)(ws + 3145728);
    short* wpb = (short*)(ws + 3670016);
    short* qb  = (short*)(ws + 4194304);     // 2 MB
    short* kb  = (short*)(ws + 6291456);     // 2 MB
    short* vT  = (short*)(ws + 8388608);     // 2 MB
    short* oh  = (short*)(ws + 10485760);    // 2 MB
    short* eb  = (short*)(ws + 12582912);    // 32 MB
    float* rowsum = (float*)(ws + 46137344); // 64 KB (B*H*N)
    float* colsum = (float*)(ws + 46202880); // 4 KB  (B*H*64)

    cast_kernel<<<4096, 256, 0, stream>>>(x, Wq, Wk, Wv, Wp, xb, wqb, wkb, wvb, wpb, rowsum);
    qkv_kernel<<<dim3(8, 32, 3), 256, 0, stream>>>(xb, wqb, wkb, wvb, qb, kb, vT);
    colsum_kernel<<<16, 256, 0, stream>>>(vT, colsum);
    scores_attn_kernel<<<dim3(16, 16, 16), 256, 0, stream>>>(qb, kb, idx, attn, eb, rowsum);
    pv_kernel<<<dim3(1, 16, 16), 256, 0, stream>>>(eb, vT, rowsum, colsum, oh);
    proj_kernel<<<dim3(8, 32, 1), 256, 0, stream>>>(oh, wpb, bproj, out);
}

// Round 3
// 607.303 us; speedup vs baseline: 2.3444x; 2.3444x over previous
//
#include <hip/hip_runtime.h>
#include <hip/hip_bf16.h>
#include <cstdint>
#include <cstddef>

// Problem constants (B=2, N=1024, C=512, H=8, hd=64, clusters=8)
#define NB   2
#define NN   1024
#define NC   512
#define NH   8
#define NHD  64
#define NK   8

typedef __attribute__((ext_vector_type(8))) short short8v;   // 8 bf16 (4 VGPRs)
typedef __attribute__((ext_vector_type(4))) short short4v;
typedef __attribute__((ext_vector_type(4))) float f32x4;

__device__ __forceinline__ short f2bf(float f) {
    union { float f; unsigned u; } v; v.f = f;
    unsigned r = v.u + 0x7FFFu + ((v.u >> 16) & 1u);   // RNE
    return (short)(r >> 16);
}
__device__ __forceinline__ float bf2f(short s) {
    union { unsigned u; float f; } v;
    v.u = ((unsigned)(unsigned short)s) << 16;
    return v.f;
}

// ---------------------------------------------------------------- cast f32->bf16 (+ zero rowsum)
__global__ __launch_bounds__(256) void cast_kernel(
    const float* __restrict__ x, const float* __restrict__ wq,
    const float* __restrict__ wk, const float* __restrict__ wv,
    const float* __restrict__ wp,
    short* __restrict__ xb, short* __restrict__ wqb, short* __restrict__ wkb,
    short* __restrict__ wvb, short* __restrict__ wpb,
    float* __restrict__ rowsum) {
    int i = blockIdx.x * 256 + threadIdx.x;
    if (i < NB * NN * NC) xb[i] = f2bf(x[i]);
    if (i < NC * NC) {
        wqb[i] = f2bf(wq[i]);
        wkb[i] = f2bf(wk[i]);
        wvb[i] = f2bf(wv[i]);
        wpb[i] = f2bf(wp[i]);
    }
    if (i < NB * NH * NN) rowsum[i] = 0.f;
}

// ---------------------------------------------------------------- QKV GEMM
// q/k: (2048,512) bf16.  v stored transposed per head: vT[b,h,d,i] bf16.
__global__ __launch_bounds__(256) void qkv_kernel(
    const short* __restrict__ xb, const short* __restrict__ wqb,
    const short* __restrict__ wkb, const short* __restrict__ wvb,
    short* __restrict__ qb, short* __restrict__ kb, short* __restrict__ vT) {
    __shared__ short As[64][40];
    __shared__ short Bs[64][40];
    const int tid = threadIdx.x;
    const int z = blockIdx.z;
    const short* Bsrc = (z == 0) ? wqb : ((z == 1) ? wkb : wvb);
    const int m0 = blockIdx.y * 64, n0 = blockIdx.x * 64;
    const int lane = tid & 63, wave = tid >> 6;
    const int wm = wave >> 1, wn = wave & 1, quad = lane >> 4, lr = lane & 15;
    const int row = tid >> 2, c0 = (tid & 3) * 8;
    f32x4 acc[2][2] = {};
    for (int kt = 0; kt < 512; kt += 32) {
        *(short8v*)&As[row][c0] = *(const short8v*)(xb + (m0 + row) * 512 + kt + c0);
        *(short8v*)&Bs[row][c0] = *(const short8v*)(Bsrc + (n0 + row) * 512 + kt + c0);
        __syncthreads();
        short8v a0 = *(short8v*)&As[wm * 32 + lr][quad * 8];
        short8v a1 = *(short8v*)&As[wm * 32 + 16 + lr][quad * 8];
        short8v b0 = *(short8v*)&Bs[wn * 32 + lr][quad * 8];
        short8v b1 = *(short8v*)&Bs[wn * 32 + 16 + lr][quad * 8];
        acc[0][0] = __builtin_amdgcn_mfma_f32_16x16x32_bf16(a0, b0, acc[0][0], 0, 0, 0);
        acc[0][1] = __builtin_amdgcn_mfma_f32_16x16x32_bf16(a0, b1, acc[0][1], 0, 0, 0);
        acc[1][0] = __builtin_amdgcn_mfma_f32_16x16x32_bf16(a1, b0, acc[1][0], 0, 0, 0);
        acc[1][1] = __builtin_amdgcn_mfma_f32_16x16x32_bf16(a1, b1, acc[1][1], 0, 0, 0);
        __syncthreads();
    }
    for (int sm = 0; sm < 2; sm++)
        for (int sn = 0; sn < 2; sn++)
            for (int r = 0; r < 4; r++) {
                int m = m0 + wm * 32 + sm * 16 + quad * 4 + r;
                int n = n0 + wn * 32 + sn * 16 + lr;
                short v = f2bf(acc[sm][sn][r]);
                if (z == 0) qb[m * 512 + n] = v;
                else if (z == 1) kb[m * 512 + n] = v;
                else {
                    int bb = m >> 10, i = m & 1023, h = n >> 6, d = n & 63;
                    vT[(size_t)(((bb * 8 + h) * 64 + d) << 10) + i] = v;
                }
            }
}

// ---------------------------------------------------------------- colsum of v per (b,h)
__global__ __launch_bounds__(256) void colsum_kernel(
    const short* __restrict__ vT, float* __restrict__ colsum) {
    __shared__ float cp[64][5];
    const int bh = blockIdx.x, t = threadIdx.x;
    const int d = t >> 2, seg = t & 3;
    const short* p = vT + (((size_t)(bh * 64 + d)) << 10) + seg * 256;
    float s = 0.f;
    for (int k = 0; k < 256; k += 8) {
        short8v v = *(const short8v*)(p + k);
        for (int j = 0; j < 8; j++) s += bf2f(v[j]);
    }
    cp[d][seg] = s;
    __syncthreads();
    if (t < 64) colsum[bh * 64 + t] = cp[t][0] + cp[t][1] + cp[t][2] + cp[t][3];
}

// ---------------------------------------------------------------- fused scores + mask + attn_map scatter + exp
// Epilogue mapping: thread t -> row t>>4 (+16*ii), cols (t&15)*4.
// Per store instruction a wave covers 4 rows x 256B contiguous = 16 FULL 64B
// lines -> safe for nontemporal streaming (no partial-line RMW).
__global__ __launch_bounds__(256) void scores_attn_kernel(
    const short* __restrict__ qb, const short* __restrict__ kb,
    const int* __restrict__ idx, float* __restrict__ attn,
    short* __restrict__ eb, float* __restrict__ rowsum) {
    __shared__ short As[64][72];
    __shared__ short Bs[64][72];
    __shared__ float Ss[64][68];
    __shared__ int idxi[64], idxj[64];
    __shared__ float rowpart[64][17];
    const int tid = threadIdx.x;
    const int z = blockIdx.z;            // b*8 + h
    const int b = z >> 3, h = z & 7;
    const int i0 = blockIdx.y * 64, j0 = blockIdx.x * 64;
    const int lane = tid & 63, wave = tid >> 6;
    const int wm = wave >> 1, wn = wave & 1, quad = lane >> 4, lr = lane & 15;
    {
        int r0 = tid >> 3, cc = (tid & 7) * 8;
        *(short8v*)&As[r0][cc]      = *(const short8v*)(qb + (b * 1024 + i0 + r0) * 512 + h * 64 + cc);
        *(short8v*)&As[r0 + 32][cc] = *(const short8v*)(qb + (b * 1024 + i0 + r0 + 32) * 512 + h * 64 + cc);
        *(short8v*)&Bs[r0][cc]      = *(const short8v*)(kb + (b * 1024 + j0 + r0) * 512 + h * 64 + cc);
        *(short8v*)&Bs[r0 + 32][cc] = *(const short8v*)(kb + (b * 1024 + j0 + r0 + 32) * 512 + h * 64 + cc);
        if (tid < 64) idxi[tid] = idx[b * 1024 + i0 + tid];
        else if (tid < 128) idxj[tid - 64] = idx[b * 1024 + j0 + (tid - 64)];
    }
    __syncthreads();
    f32x4 acc[2][2] = {};
    for (int k0 = 0; k0 < 64; k0 += 32) {
        short8v a0 = *(short8v*)&As[wm * 32 + lr][k0 + quad * 8];
        short8v a1 = *(short8v*)&As[wm * 32 + 16 + lr][k0 + quad * 8];
        short8v b0 = *(short8v*)&Bs[wn * 32 + lr][k0 + quad * 8];
        short8v b1 = *(short8v*)&Bs[wn * 32 + 16 + lr][k0 + quad * 8];
        acc[0][0] = __builtin_amdgcn_mfma_f32_16x16x32_bf16(a0, b0, acc[0][0], 0, 0, 0);
        acc[0][1] = __builtin_amdgcn_mfma_f32_16x16x32_bf16(a0, b1, acc[0][1], 0, 0, 0);
        acc[1][0] = __builtin_amdgcn_mfma_f32_16x16x32_bf16(a1, b0, acc[1][0], 0, 0, 0);
        acc[1][1] = __builtin_amdgcn_mfma_f32_16x16x32_bf16(a1, b1, acc[1][1], 0, 0, 0);
    }
    // s tile -> LDS (scaled)
    for (int sm = 0; sm < 2; sm++)
        for (int sn = 0; sn < 2; sn++)
            for (int r = 0; r < 4; r++)
                Ss[wm * 32 + sm * 16 + quad * 4 + r][wn * 32 + sn * 16 + lr] = acc[sm][sn][r] * 0.125f;
    __syncthreads();
    // epilogue: coalesced rows
    const int rL = tid >> 4;          // 0..15
    const int cL = (tid & 15) * 4;    // 0..60
    const f32x4 zero4 = {0.f, 0.f, 0.f, 0.f};
    for (int ii = 0; ii < 4; ii++) {
        const int row = ii * 16 + rL;
        const int ci = idxi[row];
        f32x4 s4 = *(f32x4*)&Ss[row][cL];
        f32x4 m4;
        short4v e4;
        float rsum = 0.f;
        for (int kk = 0; kk < 4; kk++) {
            const bool in = (idxj[cL + kk] == ci);
            const float sv = s4[kk];
            m4[kk] = in ? sv : 0.f;
            const float ev = (in && sv != 0.f) ? __expf(sv) : 0.f;
            rsum += ev;
            e4[kk] = f2bf(ev);
        }
        rowpart[row][tid & 15] = rsum;
        float* base = attn + (((size_t)(b * 64 + h)) << 20) + (((size_t)(i0 + row)) << 10) + j0 + cL;
        for (int c = 0; c < 8; c++) {
            f32x4 w = (c == ci) ? m4 : zero4;
            __builtin_nontemporal_store(w, (f32x4*)(base + ((size_t)c << 23)));
        }
        *(short4v*)(eb + ((((size_t)z << 10) + i0 + row) << 10) + j0 + cL) = e4;
    }
    __syncthreads();
    if (tid < 64) {
        float v = 0.f;
        for (int s = 0; s < 16; s++) v += rowpart[tid][s];
        atomicAdd(&rowsum[(z << 10) + i0 + tid], v);
    }
}

// ---------------------------------------------------------------- PV GEMM: oh = inv * (e @ v + epsN*colsum)
__global__ __launch_bounds__(256) void pv_kernel(
    const short* __restrict__ eb, const short* __restrict__ vT,
    const float* __restrict__ rowsum, const float* __restrict__ colsum,
    short* __restrict__ oh) {
    __shared__ short As[64][40];
    __shared__ short Bs[64][40];
    __shared__ float invL[64], csL[64];
    const int tid = threadIdx.x;
    const int z = blockIdx.z;            // b*8+h
    const int b = z >> 3, h = z & 7;
    const int i0 = blockIdx.y * 64;
    const int lane = tid & 63, wave = tid >> 6;
    const int wm = wave >> 1, wn = wave & 1, quad = lane >> 4, lr = lane & 15;
    const int row = tid >> 2, c0 = (tid & 3) * 8;
    if (tid < 64) invL[tid] = 1.f / (rowsum[(z << 10) + i0 + tid] + 1e-6f);
    else if (tid < 128) csL[tid - 64] = colsum[z * 64 + (tid - 64)];
    const short* Abase = eb + ((size_t)(z * 1024 + i0) << 10);
    const short* Bbase = vT + ((size_t)z << 16);
    f32x4 acc[2][2] = {};
    for (int kt = 0; kt < 1024; kt += 32) {
        *(short8v*)&As[row][c0] = *(const short8v*)(Abase + ((size_t)row << 10) + kt + c0);
        *(short8v*)&Bs[row][c0] = *(const short8v*)(Bbase + ((size_t)row << 10) + kt + c0);
        __syncthreads();
        short8v a0 = *(short8v*)&As[wm * 32 + lr][quad * 8];
        short8v a1 = *(short8v*)&As[wm * 32 + 16 + lr][quad * 8];
        short8v b0 = *(short8v*)&Bs[wn * 32 + lr][quad * 8];
        short8v b1 = *(short8v*)&Bs[wn * 32 + 16 + lr][quad * 8];
        acc[0][0] = __builtin_amdgcn_mfma_f32_16x16x32_bf16(a0, b0, acc[0][0], 0, 0, 0);
        acc[0][1] = __builtin_amdgcn_mfma_f32_16x16x32_bf16(a0, b1, acc[0][1], 0, 0, 0);
        acc[1][0] = __builtin_amdgcn_mfma_f32_16x16x32_bf16(a1, b0, acc[1][0], 0, 0, 0);
        acc[1][1] = __builtin_amdgcn_mfma_f32_16x16x32_bf16(a1, b1, acc[1][1], 0, 0, 0);
        __syncthreads();
    }
    const float epsN = 1e-6f / 1024.f;
    for (int sm = 0; sm < 2; sm++)
        for (int sn = 0; sn < 2; sn++)
            for (int r = 0; r < 4; r++) {
                int iLoc = wm * 32 + sm * 16 + quad * 4 + r;
                int d = wn * 32 + sn * 16 + lr;
                float val = (acc[sm][sn][r] + epsN * csL[d]) * invL[iLoc];
                oh[((size_t)(b * 1024 + i0 + iLoc)) * 512 + h * 64 + d] = f2bf(val);
            }
}

// ---------------------------------------------------------------- proj GEMM + bias
__global__ __launch_bounds__(256) void proj_kernel(
    const short* __restrict__ oh, const short* __restrict__ wpb,
    const float* __restrict__ bias, float* __restrict__ out) {
    __shared__ short As[64][40];
    __shared__ short Bs[64][40];
    const int tid = threadIdx.x;
    const int m0 = blockIdx.y * 64, n0 = blockIdx.x * 64;
    const int lane = tid & 63, wave = tid >> 6;
    const int wm = wave >> 1, wn = wave & 1, quad = lane >> 4, lr = lane & 15;
    const int row = tid >> 2, c0 = (tid & 3) * 8;
    f32x4 acc[2][2] = {};
    for (int kt = 0; kt < 512; kt += 32) {
        *(short8v*)&As[row][c0] = *(const short8v*)(oh + (m0 + row) * 512 + kt + c0);
        *(short8v*)&Bs[row][c0] = *(const short8v*)(wpb + (n0 + row) * 512 + kt + c0);
        __syncthreads();
        short8v a0 = *(short8v*)&As[wm * 32 + lr][quad * 8];
        short8v a1 = *(short8v*)&As[wm * 32 + 16 + lr][quad * 8];
        short8v b0 = *(short8v*)&Bs[wn * 32 + lr][quad * 8];
        short8v b1 = *(short8v*)&Bs[wn * 32 + 16 + lr][quad * 8];
        acc[0][0] = __builtin_amdgcn_mfma_f32_16x16x32_bf16(a0, b0, acc[0][0], 0, 0, 0);
        acc[0][1] = __builtin_amdgcn_mfma_f32_16x16x32_bf16(a0, b1, acc[0][1], 0, 0, 0);
        acc[1][0] = __builtin_amdgcn_mfma_f32_16x16x32_bf16(a1, b0, acc[1][0], 0, 0, 0);
        acc[1][1] = __builtin_amdgcn_mfma_f32_16x16x32_bf16(a1, b1, acc[1][1], 0, 0, 0);
        __syncthreads();
    }
    for (int sm = 0; sm < 2; sm++)
        for (int sn = 0; sn < 2; sn++)
            for (int r = 0; r < 4; r++) {
                int m = m0 + wm * 32 + sm * 16 + quad * 4 + r;
                int n = n0 + wn * 32 + sn * 16 + lr;
                out[(size_t)m * 512 + n] = acc[sm][sn][r] + bias[n];
            }
}

// ---------------------------------------------------------------- launch
extern "C" void kernel_launch(void* const* d_in, const int* in_sizes, int n_in,
                              void* d_out, int out_size, void* d_ws, size_t ws_size,
                              hipStream_t stream) {
    const float* x     = (const float*)d_in[0];
    const int*   idx   = (const int*)d_in[2];
    const float* Wq    = (const float*)d_in[4];
    const float* Wk    = (const float*)d_in[5];
    const float* Wv    = (const float*)d_in[6];
    const float* Wp    = (const float*)d_in[7];
    const float* bproj = (const float*)d_in[8];

    float* out  = (float*)d_out;
    float* attn = out + (size_t)NB * NN * NC;   // attn_map region (B,K,H,N,N)

    char* ws = (char*)d_ws;
    short* xb  = (short*)(ws + 0);           // 2 MB
    short* wqb = (short*)(ws + 2097152);     // 512 KB
    short* wkb = (short*)(ws + 2621440);
    short* wvb = (short*)(ws + 3145728);
    short* wpb = (short*)(ws + 3670016);
    short* qb  = (short*)(ws + 4194304);     // 2 MB
    short* kb  = (short*)(ws + 6291456);     // 2 MB
    short* vT  = (short*)(ws + 8388608);     // 2 MB
    short* oh  = (short*)(ws + 10485760);    // 2 MB
    short* eb  = (short*)(ws + 12582912);    // 32 MB
    float* rowsum = (float*)(ws + 46137344); // 64 KB (B*H*N)
    float* colsum = (float*)(ws + 46202880); // 4 KB  (B*H*64)

    cast_kernel<<<4096, 256, 0, stream>>>(x, Wq, Wk, Wv, Wp, xb, wqb, wkb, wvb, wpb, rowsum);
    qkv_kernel<<<dim3(8, 32, 3), 256, 0, stream>>>(xb, wqb, wkb, wvb, qb, kb, vT);
    colsum_kernel<<<16, 256, 0, stream>>>(vT, colsum);
    scores_attn_kernel<<<dim3(16, 16, 16), 256, 0, stream>>>(qb, kb, idx, attn, eb, rowsum);
    pv_kernel<<<dim3(1, 16, 16), 256, 0, stream>>>(eb, vT, rowsum, colsum, oh);
    proj_kernel<<<dim3(8, 32, 1), 256, 0, stream>>>(oh, wpb, bproj, out);
}

// Round 4
// 595.716 us; speedup vs baseline: 2.3900x; 1.0195x over previous
//
#include <hip/hip_runtime.h>
#include <hip/hip_bf16.h>
#include <cstdint>
#include <cstddef>

// Problem constants (B=2, N=1024, C=512, H=8, hd=64, clusters=8)
#define NB   2
#define NN   1024
#define NC   512
#define NH   8
#define NHD  64
#define NK   8

typedef __attribute__((ext_vector_type(8))) short short8v;   // 8 bf16 (4 VGPRs)
typedef __attribute__((ext_vector_type(4))) short short4v;
typedef __attribute__((ext_vector_type(4))) float f32x4;

__device__ __forceinline__ short f2bf(float f) {
    union { float f; unsigned u; } v; v.f = f;
    unsigned r = v.u + 0x7FFFu + ((v.u >> 16) & 1u);   // RNE
    return (short)(r >> 16);
}
__device__ __forceinline__ float bf2f(short s) {
    union { unsigned u; float f; } v;
    v.u = ((unsigned)(unsigned short)s) << 16;
    return v.f;
}

// ---------------------------------------------------------------- zero attn rows where idx[i] != c
// attn layout (B,K,H,N,N): index = ((b*64 + c*8 + h)*1024 + i)*1024 + j
// Rows with idx[b,i]==c are skipped here; scores_attn writes those densely.
__global__ __launch_bounds__(256) void zero_attn_kernel(
    const int* __restrict__ idx, float* __restrict__ attn) {
    __shared__ int rowskip[32];
    const int blk = blockIdx.x;              // ((b*8+c)*8+h)*32 + itile
    const int itile = blk & 31, bch = blk >> 5;   // bch = b*64 + c*8 + h
    const int c = (bch >> 3) & 7, b = bch >> 6;
    const int t = threadIdx.x;
    if (t < 32) rowskip[t] = (idx[b * 1024 + itile * 32 + t] == c);
    __syncthreads();
    float* base = attn + ((size_t)bch << 20) + ((size_t)itile << 15);
    const f32x4 z = {0.f, 0.f, 0.f, 0.f};
    for (int rr = 0; rr < 32; rr++) {
        if (rowskip[rr]) continue;
        __builtin_nontemporal_store(z, (f32x4*)(base + (rr << 10) + t * 4));
    }
}

// ---------------------------------------------------------------- cast f32->bf16 (+ zero rowsum)
__global__ __launch_bounds__(256) void cast_kernel(
    const float* __restrict__ x, const float* __restrict__ wq,
    const float* __restrict__ wk, const float* __restrict__ wv,
    const float* __restrict__ wp,
    short* __restrict__ xb, short* __restrict__ wqb, short* __restrict__ wkb,
    short* __restrict__ wvb, short* __restrict__ wpb,
    float* __restrict__ rowsum) {
    int i = blockIdx.x * 256 + threadIdx.x;
    if (i < NB * NN * NC) xb[i] = f2bf(x[i]);
    if (i < NC * NC) {
        wqb[i] = f2bf(wq[i]);
        wkb[i] = f2bf(wk[i]);
        wvb[i] = f2bf(wv[i]);
        wpb[i] = f2bf(wp[i]);
    }
    if (i < NB * NH * NN) rowsum[i] = 0.f;
}

// ---------------------------------------------------------------- QKV GEMM
// q/k: (2048,512) bf16.  v stored transposed per head: vT[b,h,d,i] bf16.
__global__ __launch_bounds__(256) void qkv_kernel(
    const short* __restrict__ xb, const short* __restrict__ wqb,
    const short* __restrict__ wkb, const short* __restrict__ wvb,
    short* __restrict__ qb, short* __restrict__ kb, short* __restrict__ vT) {
    __shared__ short As[64][40];
    __shared__ short Bs[64][40];
    const int tid = threadIdx.x;
    const int z = blockIdx.z;
    const short* Bsrc = (z == 0) ? wqb : ((z == 1) ? wkb : wvb);
    const int m0 = blockIdx.y * 64, n0 = blockIdx.x * 64;
    const int lane = tid & 63, wave = tid >> 6;
    const int wm = wave >> 1, wn = wave & 1, quad = lane >> 4, lr = lane & 15;
    const int row = tid >> 2, c0 = (tid & 3) * 8;
    f32x4 acc[2][2] = {};
    for (int kt = 0; kt < 512; kt += 32) {
        *(short8v*)&As[row][c0] = *(const short8v*)(xb + (m0 + row) * 512 + kt + c0);
        *(short8v*)&Bs[row][c0] = *(const short8v*)(Bsrc + (n0 + row) * 512 + kt + c0);
        __syncthreads();
        short8v a0 = *(short8v*)&As[wm * 32 + lr][quad * 8];
        short8v a1 = *(short8v*)&As[wm * 32 + 16 + lr][quad * 8];
        short8v b0 = *(short8v*)&Bs[wn * 32 + lr][quad * 8];
        short8v b1 = *(short8v*)&Bs[wn * 32 + 16 + lr][quad * 8];
        acc[0][0] = __builtin_amdgcn_mfma_f32_16x16x32_bf16(a0, b0, acc[0][0], 0, 0, 0);
        acc[0][1] = __builtin_amdgcn_mfma_f32_16x16x32_bf16(a0, b1, acc[0][1], 0, 0, 0);
        acc[1][0] = __builtin_amdgcn_mfma_f32_16x16x32_bf16(a1, b0, acc[1][0], 0, 0, 0);
        acc[1][1] = __builtin_amdgcn_mfma_f32_16x16x32_bf16(a1, b1, acc[1][1], 0, 0, 0);
        __syncthreads();
    }
    for (int sm = 0; sm < 2; sm++)
        for (int sn = 0; sn < 2; sn++)
            for (int r = 0; r < 4; r++) {
                int m = m0 + wm * 32 + sm * 16 + quad * 4 + r;
                int n = n0 + wn * 32 + sn * 16 + lr;
                short v = f2bf(acc[sm][sn][r]);
                if (z == 0) qb[m * 512 + n] = v;
                else if (z == 1) kb[m * 512 + n] = v;
                else {
                    int bb = m >> 10, i = m & 1023, h = n >> 6, d = n & 63;
                    vT[(size_t)(((bb * 8 + h) * 64 + d) << 10) + i] = v;
                }
            }
}

// ---------------------------------------------------------------- colsum of v per (b,h)
__global__ __launch_bounds__(256) void colsum_kernel(
    const short* __restrict__ vT, float* __restrict__ colsum) {
    __shared__ float cp[8][33];
    const int blk = blockIdx.x;     // bh*8 + dgroup
    const int bh = blk >> 3, dg = blk & 7;
    const int t = threadIdx.x;
    const int dl = t >> 5, seg = t & 31;
    const short* p = vT + (((size_t)(bh * 64 + dg * 8 + dl)) << 10) + seg * 32;
    float s = 0.f;
    for (int k = 0; k < 32; k += 8) {
        short8v v = *(const short8v*)(p + k);
        for (int j = 0; j < 8; j++) s += bf2f(v[j]);
    }
    cp[dl][seg] = s;
    __syncthreads();
    if (t < 8) {
        float v = 0.f;
        for (int s2 = 0; s2 < 32; s2++) v += cp[t][s2];
        colsum[bh * 64 + dg * 8 + t] = v;
    }
}

// ---------------------------------------------------------------- fused scores + mask + ci-slice write + exp
// Only writes the c=idx[i] slice rows (zero_attn covered the rest).
__global__ __launch_bounds__(256) void scores_attn_kernel(
    const short* __restrict__ qb, const short* __restrict__ kb,
    const int* __restrict__ idx, float* __restrict__ attn,
    short* __restrict__ eb, float* __restrict__ rowsum) {
    __shared__ short As[64][72];
    __shared__ short Bs[64][72];
    __shared__ float Ss[64][68];
    __shared__ int idxi[64], idxj[64];
    __shared__ float rowpart[64][17];
    const int tid = threadIdx.x;
    const int z = blockIdx.z;            // b*8 + h
    const int b = z >> 3, h = z & 7;
    const int i0 = blockIdx.y * 64, j0 = blockIdx.x * 64;
    const int lane = tid & 63, wave = tid >> 6;
    const int wm = wave >> 1, wn = wave & 1, quad = lane >> 4, lr = lane & 15;
    {
        int r0 = tid >> 3, cc = (tid & 7) * 8;
        *(short8v*)&As[r0][cc]      = *(const short8v*)(qb + (b * 1024 + i0 + r0) * 512 + h * 64 + cc);
        *(short8v*)&As[r0 + 32][cc] = *(const short8v*)(qb + (b * 1024 + i0 + r0 + 32) * 512 + h * 64 + cc);
        *(short8v*)&Bs[r0][cc]      = *(const short8v*)(kb + (b * 1024 + j0 + r0) * 512 + h * 64 + cc);
        *(short8v*)&Bs[r0 + 32][cc] = *(const short8v*)(kb + (b * 1024 + j0 + r0 + 32) * 512 + h * 64 + cc);
        if (tid < 64) idxi[tid] = idx[b * 1024 + i0 + tid];
        else if (tid < 128) idxj[tid - 64] = idx[b * 1024 + j0 + (tid - 64)];
    }
    __syncthreads();
    f32x4 acc[2][2] = {};
    for (int k0 = 0; k0 < 64; k0 += 32) {
        short8v a0 = *(short8v*)&As[wm * 32 + lr][k0 + quad * 8];
        short8v a1 = *(short8v*)&As[wm * 32 + 16 + lr][k0 + quad * 8];
        short8v b0 = *(short8v*)&Bs[wn * 32 + lr][k0 + quad * 8];
        short8v b1 = *(short8v*)&Bs[wn * 32 + 16 + lr][k0 + quad * 8];
        acc[0][0] = __builtin_amdgcn_mfma_f32_16x16x32_bf16(a0, b0, acc[0][0], 0, 0, 0);
        acc[0][1] = __builtin_amdgcn_mfma_f32_16x16x32_bf16(a0, b1, acc[0][1], 0, 0, 0);
        acc[1][0] = __builtin_amdgcn_mfma_f32_16x16x32_bf16(a1, b0, acc[1][0], 0, 0, 0);
        acc[1][1] = __builtin_amdgcn_mfma_f32_16x16x32_bf16(a1, b1, acc[1][1], 0, 0, 0);
    }
    // s tile -> LDS (scaled)
    for (int sm = 0; sm < 2; sm++)
        for (int sn = 0; sn < 2; sn++)
            for (int r = 0; r < 4; r++)
                Ss[wm * 32 + sm * 16 + quad * 4 + r][wn * 32 + sn * 16 + lr] = acc[sm][sn][r] * 0.125f;
    __syncthreads();
    // epilogue: thread t -> row (ii*16 + t>>4), cols (t&15)*4 (coalesced rows)
    const int rL = tid >> 4;          // 0..15
    const int cL = (tid & 15) * 4;    // 0..60
    for (int ii = 0; ii < 4; ii++) {
        const int row = ii * 16 + rL;
        const int ci = idxi[row];
        f32x4 s4 = *(f32x4*)&Ss[row][cL];
        f32x4 m4;
        short4v e4;
        float rsum = 0.f;
        for (int kk = 0; kk < 4; kk++) {
            const bool in = (idxj[cL + kk] == ci);
            const float sv = s4[kk];
            m4[kk] = in ? sv : 0.f;
            const float ev = (in && sv != 0.f) ? __expf(sv) : 0.f;
            rsum += ev;
            e4[kk] = f2bf(ev);
        }
        rowpart[row][tid & 15] = rsum;
        // write only the ci slice: bch = b*64 + ci*8 + h
        float* base = attn + (((size_t)(b * 64 + ci * 8 + h)) << 20) + (((size_t)(i0 + row)) << 10) + j0 + cL;
        __builtin_nontemporal_store(m4, (f32x4*)base);
        *(short4v*)(eb + ((((size_t)z << 10) + i0 + row) << 10) + j0 + cL) = e4;
    }
    __syncthreads();
    if (tid < 64) {
        float v = 0.f;
        for (int s = 0; s < 16; s++) v += rowpart[tid][s];
        atomicAdd(&rowsum[(z << 10) + i0 + tid], v);
    }
}

// ---------------------------------------------------------------- PV GEMM: oh = inv * (e @ v + epsN*colsum)
// 32-row tiles -> 512 blocks (2 blocks/CU) for latency hiding.
__global__ __launch_bounds__(256) void pv_kernel(
    const short* __restrict__ eb, const short* __restrict__ vT,
    const float* __restrict__ rowsum, const float* __restrict__ colsum,
    short* __restrict__ oh) {
    __shared__ short As[32][40];
    __shared__ short Bs[64][40];
    __shared__ float invL[32], csL[64];
    const int tid = threadIdx.x;
    const int z = blockIdx.z;            // b*8+h
    const int b = z >> 3, h = z & 7;
    const int i0 = blockIdx.y * 32;
    const int lane = tid & 63, wave = tid >> 6;
    const int wm = wave >> 1, wn = wave & 1, quad = lane >> 4, lr = lane & 15;
    if (tid < 32) invL[tid] = 1.f / (rowsum[(z << 10) + i0 + tid] + 1e-6f);
    else if (tid < 96) csL[tid - 32] = colsum[z * 64 + (tid - 32)];
    const short* Abase = eb + ((size_t)(z * 1024 + i0) << 10);
    const short* Bbase = vT + ((size_t)z << 16);
    const int rowS = tid >> 2, c0 = (tid & 3) * 8;
    f32x4 acc[2] = {};
    for (int kt = 0; kt < 1024; kt += 32) {
        if (tid < 128)
            *(short8v*)&As[rowS][c0] = *(const short8v*)(Abase + ((size_t)rowS << 10) + kt + c0);
        *(short8v*)&Bs[rowS & 63][c0] = *(const short8v*)(Bbase + ((size_t)(rowS & 63) << 10) + kt + c0);
        __syncthreads();
        short8v a0 = *(short8v*)&As[wm * 16 + lr][quad * 8];
        short8v b0 = *(short8v*)&Bs[wn * 32 + lr][quad * 8];
        short8v b1 = *(short8v*)&Bs[wn * 32 + 16 + lr][quad * 8];
        acc[0] = __builtin_amdgcn_mfma_f32_16x16x32_bf16(a0, b0, acc[0], 0, 0, 0);
        acc[1] = __builtin_amdgcn_mfma_f32_16x16x32_bf16(a0, b1, acc[1], 0, 0, 0);
        __syncthreads();
    }
    const float epsN = 1e-6f / 1024.f;
    for (int sn = 0; sn < 2; sn++)
        for (int r = 0; r < 4; r++) {
            int iLoc = wm * 16 + quad * 4 + r;
            int d = wn * 32 + sn * 16 + lr;
            float val = (acc[sn][r] + epsN * csL[d]) * invL[iLoc];
            oh[((size_t)(b * 1024 + i0 + iLoc)) * 512 + h * 64 + d] = f2bf(val);
        }
}

// ---------------------------------------------------------------- proj GEMM + bias
__global__ __launch_bounds__(256) void proj_kernel(
    const short* __restrict__ oh, const short* __restrict__ wpb,
    const float* __restrict__ bias, float* __restrict__ out) {
    __shared__ short As[64][40];
    __shared__ short Bs[64][40];
    const int tid = threadIdx.x;
    const int m0 = blockIdx.y * 64, n0 = blockIdx.x * 64;
    const int lane = tid & 63, wave = tid >> 6;
    const int wm = wave >> 1, wn = wave & 1, quad = lane >> 4, lr = lane & 15;
    const int row = tid >> 2, c0 = (tid & 3) * 8;
    f32x4 acc[2][2] = {};
    for (int kt = 0; kt < 512; kt += 32) {
        *(short8v*)&As[row][c0] = *(const short8v*)(oh + (m0 + row) * 512 + kt + c0);
        *(short8v*)&Bs[row][c0] = *(const short8v*)(wpb + (n0 + row) * 512 + kt + c0);
        __syncthreads();
        short8v a0 = *(short8v*)&As[wm * 32 + lr][quad * 8];
        short8v a1 = *(short8v*)&As[wm * 32 + 16 + lr][quad * 8];
        short8v b0 = *(short8v*)&Bs[wn * 32 + lr][quad * 8];
        short8v b1 = *(short8v*)&Bs[wn * 32 + 16 + lr][quad * 8];
        acc[0][0] = __builtin_amdgcn_mfma_f32_16x16x32_bf16(a0, b0, acc[0][0], 0, 0, 0);
        acc[0][1] = __builtin_amdgcn_mfma_f32_16x16x32_bf16(a0, b1, acc[0][1], 0, 0, 0);
        acc[1][0] = __builtin_amdgcn_mfma_f32_16x16x32_bf16(a1, b0, acc[1][0], 0, 0, 0);
        acc[1][1] = __builtin_amdgcn_mfma_f32_16x16x32_bf16(a1, b1, acc[1][1], 0, 0, 0);
        __syncthreads();
    }
    for (int sm = 0; sm < 2; sm++)
        for (int sn = 0; sn < 2; sn++)
            for (int r = 0; r < 4; r++) {
                int m = m0 + wm * 32 + sm * 16 + quad * 4 + r;
                int n = n0 + wn * 32 + sn * 16 + lr;
                out[(size_t)m * 512 + n] = acc[sm][sn][r] + bias[n];
            }
}

// ---------------------------------------------------------------- launch
extern "C" void kernel_launch(void* const* d_in, const int* in_sizes, int n_in,
                              void* d_out, int out_size, void* d_ws, size_t ws_size,
                              hipStream_t stream) {
    const float* x     = (const float*)d_in[0];
    const int*   idx   = (const int*)d_in[2];
    const float* Wq    = (const float*)d_in[4];
    const float* Wk    = (const float*)d_in[5];
    const float* Wv    = (const float*)d_in[6];
    const float* Wp    = (const float*)d_in[7];
    const float* bproj = (const float*)d_in[8];

    float* out  = (float*)d_out;
    float* attn = out + (size_t)NB * NN * NC;   // attn_map region (B,K,H,N,N)

    char* ws = (char*)d_ws;
    short* xb  = (short*)(ws + 0);           // 2 MB
    short* wqb = (short*)(ws + 2097152);     // 512 KB
    short* wkb = (short*)(ws + 2621440);
    short* wvb = (short*)(ws + 3145728);
    short* wpb = (short*)(ws + 3670016);
    short* qb  = (short*)(ws + 4194304);     // 2 MB
    short* kb  = (short*)(ws + 6291456);     // 2 MB
    short* vT  = (short*)(ws + 8388608);     // 2 MB
    short* oh  = (short*)(ws + 10485760);    // 2 MB
    short* eb  = (short*)(ws + 12582912);    // 32 MB
    float* rowsum = (float*)(ws + 46137344); // 64 KB (B*H*N)
    float* colsum = (float*)(ws + 46202880); // 4 KB  (B*H*64)

    zero_attn_kernel<<<4096, 256, 0, stream>>>(idx, attn);
    cast_kernel<<<4096, 256, 0, stream>>>(x, Wq, Wk, Wv, Wp, xb, wqb, wkb, wvb, wpb, rowsum);
    qkv_kernel<<<dim3(8, 32, 3), 256, 0, stream>>>(xb, wqb, wkb, wvb, qb, kb, vT);
    colsum_kernel<<<128, 256, 0, stream>>>(vT, colsum);
    scores_attn_kernel<<<dim3(16, 16, 16), 256, 0, stream>>>(qb, kb, idx, attn, eb, rowsum);
    pv_kernel<<<dim3(1, 32, 16), 256, 0, stream>>>(eb, vT, rowsum, colsum, oh);
    proj_kernel<<<dim3(8, 32, 1), 256, 0, stream>>>(oh, wpb, bproj, out);
}